// Round 17
// baseline (495.463 us; speedup 1.0000x reference)
//
#include <hip/hip_runtime.h>
#include <hip/hip_bf16.h>
#include <math.h>

#define EPS_ 1e-5f
constexpr int B_ = 4, NA = 64, T_ = 128, D_ = 128, H_ = 8, L_ = 3, DFF = 512, E_ = 65536;
constexpr int DH = D_ / H_;        // 16
constexpr int NN = T_ * NA;        // 8192
constexpr int NTOT = B_ * NA * T_; // 32768
constexpr int QLD = 384;           // packed QKV bias stride
constexpr size_t NE_ = (size_t)NTOT * D_;

typedef __bf16 bf16x8 __attribute__((ext_vector_type(8)));
typedef __bf16 bf16x2 __attribute__((ext_vector_type(2)));
typedef float f32x4 __attribute__((ext_vector_type(4)));

__device__ __forceinline__ void pack_hl(float v, __bf16& hh, __bf16& ll) {
  hh = (__bf16)v;
  ll = (__bf16)(v - (float)hh);
}

// pack v into one u32: low16 = hi bf16, high16 = lo bf16 (split8's exact decomposition)
__device__ __forceinline__ unsigned pack_u32(float v) {
  __bf16 hh, ll;
  pack_hl(v, hh, ll);
  bf16x2 p;
  p[0] = hh;
  p[1] = ll;
  return __builtin_bit_cast(unsigned, p);
}

// unpack 8 packed u32 words -> bf16x8 hi + bf16x8 lo (bitwise = split8's outputs; pure bit-ops)
__device__ __forceinline__ void unpack8(const unsigned* __restrict__ p,
                                        bf16x8& hi, bf16x8& lo) {
  uint4 a = *(const uint4*)p;
  uint4 b = *(const uint4*)(p + 4);
  unsigned w[8] = {a.x, a.y, a.z, a.w, b.x, b.y, b.z, b.w};
#pragma unroll
  for (int j = 0; j < 8; ++j) {
    bf16x2 q = __builtin_bit_cast(bf16x2, w[j]);
    hi[j] = q[0];
    lo[j] = q[1];
  }
}

// ---------------- embed: x = hist@W + b ; e = x + posenc (+ packed be for attn) ----------------
__global__ __launch_bounds__(256) void embed_kernel(
    const float* __restrict__ hist, const float* __restrict__ w,
    const float* __restrict__ b, float* __restrict__ x, float* __restrict__ e,
    __bf16* __restrict__ ehi, __bf16* __restrict__ elo) {
  int idx = blockIdx.x * 256 + threadIdx.x;
  if (idx >= NTOT * D_) return;
  int d = idx & (D_ - 1);
  int r = idx >> 7;
  int t = r & (T_ - 1);
  const float* hp = hist + (size_t)r * 3;
  float acc = b[d];
  acc += hp[0] * w[0 * D_ + d];
  acc += hp[1] * w[1 * D_ + d];
  acc += hp[2] * w[2 * D_ + d];
  x[idx] = acc;
  int p = d >> 1;
  float ang = (float)t * expf(-logf(10000.f) * (2.f * (float)p) / (float)D_);
  float pe = (d & 1) ? cosf(ang) : sinf(ang);
  float ev = acc + pe;
  e[idx] = ev;
  __bf16 hh, ll;
  pack_hl(ev, hh, ll);
  ehi[idx] = hh;
  elo[idx] = ll;
}

// ---------------- weight split into FRAGMENT-LINEAR bf16 hi/lo ----------------
__global__ __launch_bounds__(256) void convert_weights(
    const float* __restrict__ wq, const float* __restrict__ wk,
    const float* __restrict__ wv, const float* __restrict__ wo,
    const float* __restrict__ w1, const float* __restrict__ w2,
    __bf16* __restrict__ hi, __bf16* __restrict__ lo) {
  const int LW = 196608;
  int idx = blockIdx.x * 256 + threadIdx.x;
  if (idx >= L_ * LW) return;
  int l = idx / LW;
  int rem = idx - l * LW;
  float src;
  int n, k, K, segoff;
  if (rem < 49152) { // qkv
    n = rem >> 7; k = rem & 127; K = 128; segoff = 0;
    int which = n >> 7, nl = n & 127;
    const float* W = (which == 0) ? wq : (which == 1) ? wk : wv;
    src = W[(size_t)l * 16384 + k * 128 + nl];
  } else if (rem < 65536) { // wo
    int r2 = rem - 49152;
    n = r2 >> 7; k = r2 & 127; K = 128; segoff = 49152;
    src = wo[(size_t)l * 16384 + k * 128 + n];
  } else if (rem < 131072) { // w1
    int r2 = rem - 65536;
    n = r2 >> 7; k = r2 & 127; K = 128; segoff = 65536;
    src = w1[(size_t)l * 65536 + k * 512 + n];
  } else { // w2
    int r2 = rem - 131072;
    n = r2 >> 9; k = r2 & 511; K = 512; segoff = 131072;
    src = w2[(size_t)l * 65536 + k * 128 + n];
  }
  int nt = n >> 4, kt = k >> 5;
  int lane = ((k >> 3) & 3) * 16 + (n & 15);
  int j = k & 7;
  int dst = l * LW + segoff + ((nt * (K / 32) + kt) * 64 + lane) * 8 + j;
  __bf16 h = (__bf16)src;
  hi[dst] = h;
  lo[dst] = (__bf16)(src - (float)h);
}

// ---------------- pack QKV biases ----------------
__global__ __launch_bounds__(256) void bias_pack(
    const float* __restrict__ bq, const float* __restrict__ bk,
    const float* __restrict__ bv, float* __restrict__ pb) {
  int idx = blockIdx.x * 256 + threadIdx.x;
  if (idx >= L_ * QLD) return;
  int l = idx / QLD, n = idx - l * QLD;
  int which = n >> 7, nl = n & 127;
  const float* src = (which == 0) ? bq : (which == 1) ? bk : bv;
  pb[idx] = src[l * 128 + nl];
}

__device__ __forceinline__ void split8(const float* __restrict__ p,
                                       bf16x8& hi, bf16x8& lo) {
  float4 x0 = *(const float4*)p;
  float4 x1 = *(const float4*)(p + 4);
  float xv[8] = {x0.x, x0.y, x0.z, x0.w, x1.x, x1.y, x1.z, x1.w};
#pragma unroll
  for (int j = 0; j < 8; ++j) {
    __bf16 h = (__bf16)xv[j];
    hi[j] = h;
    lo[j] = (__bf16)(xv[j] - (float)h);
  }
}

// ---------------- FF1 GEMM, 128x128 tile [r29: C packed as u32 (hi,lo) per element] ----------------
// r25 XCD decode; r29: epilogue packs relu(v) into one u32 dword (same store bytes/pattern as
// fp32 — HBM-neutral) so ff2_ln can unpack with bit-ops instead of split8 cvt VALU.
template <int K>
__global__ __launch_bounds__(256) void gemm_big(
    const float* __restrict__ A, int lda,
    const __bf16* __restrict__ Whi, const __bf16* __restrict__ Wlo,
    const float* __restrict__ bias,
    unsigned* __restrict__ Cpk, int ldc) {
  const int wave = threadIdx.x >> 6;
  const int lane = threadIdx.x & 63;
  const int m16 = lane & 15;
  const int quad = lane >> 4;
  const int wrow = wave >> 1, wcol = wave & 1;
  const int by = blockIdx.x & 255;  // row-block (NTOT/128 = 256)
  const int bx = blockIdx.x >> 8;   // col-block
  const int row0 = by * 128 + wrow * 64;
  const int col0 = bx * 128 + wcol * 64;
  const int ctb = col0 >> 4;

  f32x4 acc[4][4] = {};
#pragma unroll
  for (int k0 = 0; k0 < K; k0 += 32) {
    bf16x8 ahi[4], alo[4];
#pragma unroll
    for (int mf = 0; mf < 4; ++mf)
      split8(A + (size_t)(row0 + mf * 16 + m16) * lda + k0 + quad * 8, ahi[mf], alo[mf]);
    bf16x8 bhi[4], blo[4];
#pragma unroll
    for (int nf = 0; nf < 4; ++nf) {
      size_t off = ((size_t)(ctb + nf) * (K / 32) + (k0 >> 5)) * 512 + lane * 8;
      bhi[nf] = *(const bf16x8*)(Whi + off);
      blo[nf] = *(const bf16x8*)(Wlo + off);
    }
#pragma unroll
    for (int mf = 0; mf < 4; ++mf)
#pragma unroll
      for (int nf = 0; nf < 4; ++nf) {
        acc[mf][nf] = __builtin_amdgcn_mfma_f32_16x16x32_bf16(ahi[mf], bhi[nf], acc[mf][nf], 0, 0, 0);
        acc[mf][nf] = __builtin_amdgcn_mfma_f32_16x16x32_bf16(ahi[mf], blo[nf], acc[mf][nf], 0, 0, 0);
        acc[mf][nf] = __builtin_amdgcn_mfma_f32_16x16x32_bf16(alo[mf], bhi[nf], acc[mf][nf], 0, 0, 0);
      }
  }
#pragma unroll
  for (int mf = 0; mf < 4; ++mf)
#pragma unroll
    for (int nf = 0; nf < 4; ++nf) {
      int c = col0 + nf * 16 + m16;
      float bj = bias[c];
#pragma unroll
      for (int reg = 0; reg < 4; ++reg) {
        int r = row0 + mf * 16 + quad * 4 + reg;
        float v = fmaxf(acc[mf][nf][reg] + bj, 0.f);
        Cpk[(size_t)r * ldc + c] = pack_u32(v);
      }
    }
}

// ---------------- GEMM + bias + resid + LayerNorm; block 64x128, register A [r12] ----------------
template <int K>
__global__ __launch_bounds__(256) void gemm_ln(
    const float* __restrict__ A, int lda,
    const __bf16* __restrict__ Whi, const __bf16* __restrict__ Wlo,
    const float* __restrict__ bias, const float* __restrict__ resid,
    const float* __restrict__ lng, const float* __restrict__ lnb,
    float* __restrict__ C) {
  const int wave = threadIdx.x >> 6;
  const int lane = threadIdx.x & 63;
  const int m16 = lane & 15;
  const int quad = lane >> 4;
  const int wrow = wave >> 1, wcol = wave & 1;
  const int row0 = blockIdx.y * 64 + wrow * 32;
  const int col0 = wcol * 64;
  const int ctb = wcol * 4;

  f32x4 acc[2][4] = {};
#pragma unroll
  for (int k0 = 0; k0 < K; k0 += 32) {
    bf16x8 ahi[2], alo[2];
#pragma unroll
    for (int mf = 0; mf < 2; ++mf)
      split8(A + (size_t)(row0 + mf * 16 + m16) * lda + k0 + quad * 8, ahi[mf], alo[mf]);
    bf16x8 bhi[4], blo[4];
#pragma unroll
    for (int nf = 0; nf < 4; ++nf) {
      size_t off = ((size_t)(ctb + nf) * (K / 32) + (k0 >> 5)) * 512 + lane * 8;
      bhi[nf] = *(const bf16x8*)(Whi + off);
      blo[nf] = *(const bf16x8*)(Wlo + off);
    }
#pragma unroll
    for (int mf = 0; mf < 2; ++mf)
#pragma unroll
      for (int nf = 0; nf < 4; ++nf) {
        acc[mf][nf] = __builtin_amdgcn_mfma_f32_16x16x32_bf16(ahi[mf], bhi[nf], acc[mf][nf], 0, 0, 0);
        acc[mf][nf] = __builtin_amdgcn_mfma_f32_16x16x32_bf16(ahi[mf], blo[nf], acc[mf][nf], 0, 0, 0);
        acc[mf][nf] = __builtin_amdgcn_mfma_f32_16x16x32_bf16(alo[mf], bhi[nf], acc[mf][nf], 0, 0, 0);
      }
  }
  __shared__ float rs[64][2], rq[64][2];
#pragma unroll
  for (int mf = 0; mf < 2; ++mf)
#pragma unroll
    for (int reg = 0; reg < 4; ++reg) {
      int lr = wrow * 32 + mf * 16 + quad * 4 + reg;
      int gr = blockIdx.y * 64 + lr;
      float s = 0.f, qq = 0.f;
#pragma unroll
      for (int nf = 0; nf < 4; ++nf) {
        int c = col0 + nf * 16 + m16;
        float v = acc[mf][nf][reg] + bias[c] + resid[(size_t)gr * 128 + c];
        acc[mf][nf][reg] = v;
        s += v;
        qq += v * v;
      }
#pragma unroll
      for (int off = 1; off < 16; off <<= 1) {
        s += __shfl_xor(s, off, 64);
        qq += __shfl_xor(qq, off, 64);
      }
      if (m16 == 0) { rs[lr][wcol] = s; rq[lr][wcol] = qq; }
    }
  __syncthreads();
#pragma unroll
  for (int mf = 0; mf < 2; ++mf)
#pragma unroll
    for (int reg = 0; reg < 4; ++reg) {
      int lr = wrow * 32 + mf * 16 + quad * 4 + reg;
      int gr = blockIdx.y * 64 + lr;
      float mean = (rs[lr][0] + rs[lr][1]) * (1.f / 128.f);
      float var = (rq[lr][0] + rq[lr][1]) * (1.f / 128.f) - mean * mean;
      float rstd = rsqrtf(var + EPS_);
#pragma unroll
      for (int nf = 0; nf < 4; ++nf) {
        int c = col0 + nf * 16 + m16;
        C[(size_t)gr * 128 + c] = (acc[mf][nf][reg] - mean) * rstd * lng[c] + lnb[c];
      }
    }
}

// ---------------- FF2 + LN [r29: packed-u32 A, bit-unpack (no split8); r28 PACK] ----------------
template <int SDOT, int PACK>
__global__ __launch_bounds__(256) void ff2_ln(
    const unsigned* __restrict__ Apk, // ffmid packed [M][512]
    const __bf16* __restrict__ Whi, const __bf16* __restrict__ Wlo,
    const float* __restrict__ bias, const float* __restrict__ resid,
    const float* __restrict__ lng, const float* __restrict__ lnb,
    float* __restrict__ C, __bf16* __restrict__ Chi, __bf16* __restrict__ Clo,
    const float* __restrict__ bx, float* __restrict__ sdst) {
  const int wave = threadIdx.x >> 6;
  const int lane = threadIdx.x & 63;
  const int m16 = lane & 15;
  const int quad = lane >> 4;
  const int wrow = wave >> 1, wcol = wave & 1;
  const int grow0 = blockIdx.y * 64;
  const int lrow0 = wrow * 32;
  const int col0 = wcol * 64;
  const int ctb = wcol * 4;

  __shared__ unsigned As[64][129]; // identical byte layout to the proven fp32 [64][129]

  f32x4 acc[2][4] = {};
  for (int kc = 0; kc < 4; ++kc) {
    if (kc) __syncthreads();
#pragma unroll
    for (int u = 0; u < 8; ++u) {
      int unit = threadIdx.x + u * 256;
      int r = unit >> 5, c4 = unit & 31;
      uint4 v = *(const uint4*)(Apk + (size_t)(grow0 + r) * 512 + kc * 128 + c4 * 4);
      As[r][c4 * 4 + 0] = v.x;
      As[r][c4 * 4 + 1] = v.y;
      As[r][c4 * 4 + 2] = v.z;
      As[r][c4 * 4 + 3] = v.w;
    }
    __syncthreads();
#pragma unroll
    for (int kt = 0; kt < 4; ++kt) {
      bf16x8 ahi[2], alo[2];
#pragma unroll
      for (int mf = 0; mf < 2; ++mf)
        unpack8(&As[lrow0 + mf * 16 + m16][kt * 32 + quad * 8], ahi[mf], alo[mf]);
      bf16x8 bhi[4], blo[4];
#pragma unroll
      for (int nf = 0; nf < 4; ++nf) {
        size_t off = ((size_t)(ctb + nf) * 16 + (kc * 4 + kt)) * 512 + lane * 8;
        bhi[nf] = *(const bf16x8*)(Whi + off);
        blo[nf] = *(const bf16x8*)(Wlo + off);
      }
#pragma unroll
      for (int mf = 0; mf < 2; ++mf)
#pragma unroll
        for (int nf = 0; nf < 4; ++nf) {
          acc[mf][nf] = __builtin_amdgcn_mfma_f32_16x16x32_bf16(ahi[mf], bhi[nf], acc[mf][nf], 0, 0, 0);
          acc[mf][nf] = __builtin_amdgcn_mfma_f32_16x16x32_bf16(ahi[mf], blo[nf], acc[mf][nf], 0, 0, 0);
          acc[mf][nf] = __builtin_amdgcn_mfma_f32_16x16x32_bf16(alo[mf], bhi[nf], acc[mf][nf], 0, 0, 0);
        }
    }
  }
  __shared__ float rs[64][2], rq[64][2];
  __shared__ float sd[64][2];
#pragma unroll
  for (int mf = 0; mf < 2; ++mf)
#pragma unroll
    for (int reg = 0; reg < 4; ++reg) {
      int lr = lrow0 + mf * 16 + quad * 4 + reg;
      int gr = grow0 + lr;
      float s = 0.f, qq = 0.f;
#pragma unroll
      for (int nf = 0; nf < 4; ++nf) {
        int c = col0 + nf * 16 + m16;
        float v = acc[mf][nf][reg] + bias[c] + resid[(size_t)gr * 128 + c];
        acc[mf][nf][reg] = v;
        s += v;
        qq += v * v;
      }
#pragma unroll
      for (int off = 1; off < 16; off <<= 1) {
        s += __shfl_xor(s, off, 64);
        qq += __shfl_xor(qq, off, 64);
      }
      if (m16 == 0) { rs[lr][wcol] = s; rq[lr][wcol] = qq; }
    }
  __syncthreads();
#pragma unroll
  for (int mf = 0; mf < 2; ++mf)
#pragma unroll
    for (int reg = 0; reg < 4; ++reg) {
      int lr = lrow0 + mf * 16 + quad * 4 + reg;
      int gr = grow0 + lr;
      float mean = (rs[lr][0] + rs[lr][1]) * (1.f / 128.f);
      float var = (rq[lr][0] + rq[lr][1]) * (1.f / 128.f) - mean * mean;
      float rstd = rsqrtf(var + EPS_);
      float sdp = 0.f;
#pragma unroll
      for (int nf = 0; nf < 4; ++nf) {
        int c = col0 + nf * 16 + m16;
        float v = (acc[mf][nf][reg] - mean) * rstd * lng[c] + lnb[c];
        size_t oidx = (size_t)gr * 128 + c;
        C[oidx] = v;
        if (PACK) {
          __bf16 hh, ll;
          pack_hl(v, hh, ll);
          Chi[oidx] = hh;
          Clo[oidx] = ll;
        }
        if (SDOT) sdp += v * bx[oidx];
      }
      if (SDOT) {
#pragma unroll
        for (int off = 1; off < 16; off <<= 1) sdp += __shfl_xor(sdp, off, 64);
        if (m16 == 0) sd[lr][wcol] = sdp;
      }
    }
  if (SDOT) {
    __syncthreads();
    if (threadIdx.x < 64) {
      int lr = threadIdx.x;
      int gr = grow0 + lr;
      float sv = sd[lr][0] + sd[lr][1];
      int t = gr & (T_ - 1);
      int bn = gr >> 7;
      int n = bn & (NA - 1);
      int b = bn >> 6;
      sdst[(size_t)b * NN + t * NA + n] = sv;
    }
  }
}

// ---------------- FUSED QKV-GEMM + attention [r28: packed-A input; r25 XCD decode] ----------------
__global__ __launch_bounds__(256) void attn_fused(
    const __bf16* __restrict__ Ahi, const __bf16* __restrict__ Alo, // be packed [NTOT][128]
    const __bf16* __restrict__ Whi, const __bf16* __restrict__ Wlo, // layer qkv segment
    const float* __restrict__ pb,      // packed qkv bias [384]
    float* __restrict__ O) {           // [NTOT][128]
  const int h = blockIdx.x >> 8;      // head-major
  const int bn = blockIdx.x & 255;    // same-bn blocks share an XCD
  const int wave = threadIdx.x >> 6;
  const int lane = threadIdx.x & 63;
  const int m16 = lane & 15;
  const int quad = lane >> 4;
  const int row0 = wave * 32;
  const __bf16* Abh = Ahi + (size_t)bn * T_ * 128;
  const __bf16* Abl = Alo + (size_t)bn * T_ * 128;

  __shared__ __bf16 Plds[4][32][136];
  __shared__ __bf16 KVH[8][32][8], KVL[8][32][8]; // K then (post-QK^T) V, time-shared
  __bf16* QHw = &Plds[wave][0][0];                // wave-private Q: [2][32][8] (aliased)
  __bf16* QLw = QHw + 512;
  __bf16* kvh = &KVH[0][0][0];
  __bf16* kvl = &KVL[0][0][0];

  // ---- mini-GEMM: rows [row0, row0+32) x {Q,K,V} cols [h*16, h*16+16)
  f32x4 qkv[2][3] = {}; // [mf][seg]
#pragma unroll
  for (int k0 = 0; k0 < 128; k0 += 32) {
    bf16x8 ahi[2], alo[2];
#pragma unroll
    for (int mf = 0; mf < 2; ++mf) {
      size_t aoff = (size_t)(row0 + mf * 16 + m16) * 128 + k0 + quad * 8;
      ahi[mf] = *(const bf16x8*)(Abh + aoff);
      alo[mf] = *(const bf16x8*)(Abl + aoff);
    }
    bf16x8 bhi[3], blo[3];
#pragma unroll
    for (int s = 0; s < 3; ++s) {
      size_t off = ((size_t)(s * 8 + h) * 4 + (k0 >> 5)) * 512 + lane * 8; // ctb = s*8+h
      bhi[s] = *(const bf16x8*)(Whi + off);
      blo[s] = *(const bf16x8*)(Wlo + off);
    }
#pragma unroll
    for (int mf = 0; mf < 2; ++mf)
#pragma unroll
      for (int s = 0; s < 3; ++s) {
        qkv[mf][s] = __builtin_amdgcn_mfma_f32_16x16x32_bf16(ahi[mf], bhi[s], qkv[mf][s], 0, 0, 0);
        qkv[mf][s] = __builtin_amdgcn_mfma_f32_16x16x32_bf16(ahi[mf], blo[s], qkv[mf][s], 0, 0, 0);
        qkv[mf][s] = __builtin_amdgcn_mfma_f32_16x16x32_bf16(alo[mf], bhi[s], qkv[mf][s], 0, 0, 0);
      }
  }

  // ---- stage Q (wave-private) + K (shared); V stays in registers until after QK^T
#pragma unroll
  for (int mf = 0; mf < 2; ++mf)
#pragma unroll
    for (int reg = 0; reg < 4; ++reg) {
      const int tl = mf * 16 + quad * 4 + reg; // local row 0..31
      const int t = row0 + tl;                 // block row 0..127
      const int dh = m16;
      { // Q -> wave-private
        float v = qkv[mf][0][reg] + pb[h * 16 + dh];
        __bf16 hh, ll;
        pack_hl(v, hh, ll);
        int idx = mf * 256 + ((dh >> 3) * 16 + (tl & 15)) * 8 + (dh & 7);
        QHw[idx] = hh;
        QLw[idx] = ll;
      }
      { // K -> shared (K layout: [t>>4][(dh>>3)*16 + (t&15)][dh&7])
        float v = qkv[mf][1][reg] + pb[128 + h * 16 + dh];
        __bf16 hh, ll;
        pack_hl(v, hh, ll);
        int idx = ((t >> 4) * 32 + (dh >> 3) * 16 + (t & 15)) * 8 + (dh & 7);
        kvh[idx] = hh;
        kvl[idx] = ll;
      }
    }

  // ---- read own Q A-frags back (wave-private; same-wave LDS dependency)
  bf16x8 qhi[2], qlo[2];
#pragma unroll
  for (int mf = 0; mf < 2; ++mf) {
    if (quad < 2) {
      int idx = mf * 256 + (quad * 16 + m16) * 8;
      qhi[mf] = *(const bf16x8*)&QHw[idx];
      qlo[mf] = *(const bf16x8*)&QLw[idx];
    } else {
#pragma unroll
      for (int j = 0; j < 8; ++j) { qhi[mf][j] = (__bf16)0.f; qlo[mf][j] = (__bf16)0.f; }
    }
  }
  __syncthreads(); // K staging visible to all waves

  f32x4 acc[2][8] = {};
#pragma unroll
  for (int nf = 0; nf < 8; ++nf) {
    bf16x8 khi, klo;
    if (quad < 2) {
      khi = *(const bf16x8*)&kvh[(nf * 32 + lane) * 8]; // lane in [0,32)
      klo = *(const bf16x8*)&kvl[(nf * 32 + lane) * 8];
    } else {
#pragma unroll
      for (int j = 0; j < 8; ++j) { khi[j] = (__bf16)0.f; klo[j] = (__bf16)0.f; }
    }
#pragma unroll
    for (int mf = 0; mf < 2; ++mf) {
      acc[mf][nf] = __builtin_amdgcn_mfma_f32_16x16x32_bf16(qhi[mf], khi, acc[mf][nf], 0, 0, 0);
      acc[mf][nf] = __builtin_amdgcn_mfma_f32_16x16x32_bf16(qhi[mf], klo, acc[mf][nf], 0, 0, 0);
      acc[mf][nf] = __builtin_amdgcn_mfma_f32_16x16x32_bf16(qlo[mf], khi, acc[mf][nf], 0, 0, 0);
    }
  }
  __syncthreads(); // all waves done reading K -> region reusable for V

  // ---- stage V into the K region (V layout: [(t>>5)*64 + (rem>>3)*16 + dh][rem&7])
#pragma unroll
  for (int mf = 0; mf < 2; ++mf)
#pragma unroll
    for (int reg = 0; reg < 4; ++reg) {
      const int t = row0 + mf * 16 + quad * 4 + reg;
      const int dh = m16;
      float v = qkv[mf][2][reg] + pb[256 + h * 16 + dh];
      __bf16 hh, ll;
      pack_hl(v, hh, ll);
      int kc = t >> 5, rem = t & 31;
      int idx = (kc * 64 + (rem >> 3) * 16 + dh) * 8 + (rem & 7);
      kvh[idx] = hh;
      kvl[idx] = ll;
    }

  // ---- softmax (register-only; overlaps other waves' V stores)
  const float scale = 0.25f;
#pragma unroll
  for (int mf = 0; mf < 2; ++mf)
#pragma unroll
    for (int reg = 0; reg < 4; ++reg) {
      float mx = -1e30f;
#pragma unroll
      for (int nf = 0; nf < 8; ++nf) mx = fmaxf(mx, acc[mf][nf][reg]);
#pragma unroll
      for (int off = 1; off < 16; off <<= 1) mx = fmaxf(mx, __shfl_xor(mx, off, 64));
      float sum = 0.f;
#pragma unroll
      for (int nf = 0; nf < 8; ++nf) {
        float e = __expf((acc[mf][nf][reg] - mx) * scale);
        acc[mf][nf][reg] = e;
        sum += e;
      }
#pragma unroll
      for (int off = 1; off < 16; off <<= 1) sum += __shfl_xor(sum, off, 64);
      float inv = 1.f / sum;
#pragma unroll
      for (int nf = 0; nf < 8; ++nf) acc[mf][nf][reg] *= inv;
    }
  __syncthreads(); // V staging visible to all waves

#pragma unroll
  for (int mf = 0; mf < 2; ++mf)
#pragma unroll
    for (int nf = 0; nf < 8; ++nf)
#pragma unroll
      for (int reg = 0; reg < 4; ++reg)
        Plds[wave][mf * 16 + quad * 4 + reg][nf * 16 + m16] = (__bf16)acc[mf][nf][reg];

  f32x4 oacc[2] = {};
#pragma unroll
  for (int kc = 0; kc < 4; ++kc) {
    bf16x8 pa0 = *(const bf16x8*)&Plds[wave][m16][kc * 32 + quad * 8];
    bf16x8 pa1 = *(const bf16x8*)&Plds[wave][16 + m16][kc * 32 + quad * 8];
    bf16x8 vhi = *(const bf16x8*)&kvh[(kc * 64 + lane) * 8];
    bf16x8 vlo = *(const bf16x8*)&kvl[(kc * 64 + lane) * 8];
    oacc[0] = __builtin_amdgcn_mfma_f32_16x16x32_bf16(pa0, vhi, oacc[0], 0, 0, 0);
    oacc[0] = __builtin_amdgcn_mfma_f32_16x16x32_bf16(pa0, vlo, oacc[0], 0, 0, 0);
    oacc[1] = __builtin_amdgcn_mfma_f32_16x16x32_bf16(pa1, vhi, oacc[1], 0, 0, 0);
    oacc[1] = __builtin_amdgcn_mfma_f32_16x16x32_bf16(pa1, vlo, oacc[1], 0, 0, 0);
  }

#pragma unroll
  for (int mf = 0; mf < 2; ++mf)
#pragma unroll
    for (int reg = 0; reg < 4; ++reg) {
      int r = row0 + mf * 16 + quad * 4 + reg;
      O[((size_t)bn * T_ + r) * 128 + h * 16 + m16] = oacc[mf][reg];
    }
}

// ---------------- edge scatter ----------------
__global__ __launch_bounds__(256) void scatter_kernel(
    const float* __restrict__ s, const int* __restrict__ ei,
    const float* __restrict__ ew, float* __restrict__ g) {
  int idx = blockIdx.x * 256 + threadIdx.x;
  if (idx >= B_ * E_) return;
  int b = idx >> 16;
  int e = idx & (E_ - 1);
  int src = ei[(size_t)b * 2 * E_ + e];
  int dst = ei[(size_t)b * 2 * E_ + E_ + e];
  float w = ew[(size_t)b * E_ + e];
  atomicAdd(&g[(size_t)b * NN + dst], w * s[(size_t)b * NN + src]);
}

// ---------------- partial sums for global mean/var ----------------
__global__ __launch_bounds__(256) void stats_partial(
    const float* __restrict__ g, float* __restrict__ st) {
  int i = blockIdx.x * 256 + threadIdx.x;
  float v = g[i];
  float sum = v, sq = v * v;
#pragma unroll
  for (int off = 32; off; off >>= 1) {
    sum += __shfl_down(sum, off, 64);
    sq += __shfl_down(sq, off, 64);
  }
  __shared__ float s1[4], s2[4];
  int w = threadIdx.x >> 6;
  if ((threadIdx.x & 63) == 0) { s1[w] = sum; s2[w] = sq; }
  __syncthreads();
  if (threadIdx.x == 0) {
    atomicAdd(&st[0], s1[0] + s1[1] + s1[2] + s1[3]);
    atomicAdd(&st[1], s2[0] + s2[1] + s2[2] + s2[3]);
  }
}

// ---------------- final (fp32 out) ----------------
__global__ __launch_bounds__(256) void final_kernel(
    const float* __restrict__ g, const float* __restrict__ st,
    const float* __restrict__ bng, const float* __restrict__ bnb,
    const float* __restrict__ lw, const float* __restrict__ lb,
    float* __restrict__ out) {
  int idx = blockIdx.x * 256 + threadIdx.x;
  if (idx >= NTOT * D_) return;
  int d = idx & (D_ - 1);
  int r = idx >> 7;
  int t = r & (T_ - 1);
  int bn = r >> 7;
  int n = bn & (NA - 1);
  int b = bn >> 6;
  const float invn = 1.f / (float)(B_ * NN);
  float m = st[0] * invn;
  float var = st[1] * invn - m * m;
  float rs = rsqrtf(var + EPS_);
  float gv = g[(size_t)b * NN + t * NA + n];
  float val = (gv - m) * rs * bng[0] + bnb[0];
  out[idx] = val * lw[d] + lb[d];
}

extern "C" void kernel_launch(void* const* d_in, const int* in_sizes, int n_in,
                              void* d_out, int out_size, void* d_ws, size_t ws_size,
                              hipStream_t stream) {
  const float* hist = (const float*)d_in[0];
  const int* eidx = (const int*)d_in[1];
  const float* ew = (const float*)d_in[2];
  const float* hw = (const float*)d_in[3];
  const float* hb = (const float*)d_in[4];
  const float* wq = (const float*)d_in[5];
  const float* bq = (const float*)d_in[6];
  const float* wk = (const float*)d_in[7];
  const float* bk = (const float*)d_in[8];
  const float* wv = (const float*)d_in[9];
  const float* bv = (const float*)d_in[10];
  const float* wo = (const float*)d_in[11];
  const float* bo = (const float*)d_in[12];
  const float* ln1g = (const float*)d_in[13];
  const float* ln1b = (const float*)d_in[14];
  const float* w1 = (const float*)d_in[15];
  const float* b1 = (const float*)d_in[16];
  const float* w2 = (const float*)d_in[17];
  const float* b2 = (const float*)d_in[18];
  const float* ln2g = (const float*)d_in[19];
  const float* ln2b = (const float*)d_in[20];
  const float* bng = (const float*)d_in[21];
  const float* bnb = (const float*)d_in[22];
  const float* lgw = (const float*)d_in[23];
  const float* lgb = (const float*)d_in[24];
  float* out = (float*)d_out;

  float* ws = (float*)d_ws;
  const size_t NE = NE_;
  float* bx = ws + 0 * NE;
  float* be = ws + 1 * NE;
  float* h1 = ws + 2 * NE;
  float* obuf = ws + 3 * NE;  // attention output [row][128]
  unsigned* ffmid = (unsigned*)(ws + 3 * NE); // packed u32 [NTOT][512], overlaps dead obuf
  float* bs_ = ws + 7 * NE;
  float* bg_ = bs_ + NTOT;
  float* bst = bg_ + NTOT;
  float* pbias = bst + 2;
  const int LW = 196608;
  __bf16* whiB = (__bf16*)(pbias + L_ * QLD);
  __bf16* wloB = whiB + (size_t)L_ * LW;
  __bf16* behi = wloB + (size_t)L_ * LW; // packed be [NTOT][128]
  __bf16* belo = behi + NE;

  convert_weights<<<(L_ * LW + 255) / 256, 256, 0, stream>>>(
      wq, wk, wv, wo, w1, w2, whiB, wloB);
  bias_pack<<<(L_ * QLD + 255) / 256, 256, 0, stream>>>(bq, bk, bv, pbias);
  embed_kernel<<<(NTOT * D_) / 256, 256, 0, stream>>>(hist, hw, hb, bx, be, behi, belo);

  for (int l = 0; l < L_; ++l) {
    const __bf16* hiL = whiB + (size_t)l * LW;
    const __bf16* loL = wloB + (size_t)l * LW;
    attn_fused<<<B_ * NA * H_, 256, 0, stream>>>(
        behi, belo, hiL, loL, pbias + l * QLD, obuf);
    gemm_ln<128><<<dim3(1, NTOT / 64), 256, 0, stream>>>(
        obuf, 128, hiL + 49152, loL + 49152, bo + l * D_, be,
        ln1g + l * D_, ln1b + l * D_, h1);
    gemm_big<128><<<4 * (NTOT / 128), 256, 0, stream>>>(
        h1, 128, hiL + 65536, loL + 65536, b1 + l * DFF, ffmid, 512);
    if (l < L_ - 1) {
      ff2_ln<0, 1><<<dim3(1, NTOT / 64), 256, 0, stream>>>(
          ffmid, hiL + 131072, loL + 131072, b2 + l * D_, h1,
          ln2g + l * D_, ln2b + l * D_, be, behi, belo, nullptr, nullptr);
    } else {
      ff2_ln<1, 0><<<dim3(1, NTOT / 64), 256, 0, stream>>>(
          ffmid, hiL + 131072, loL + 131072, b2 + l * D_, h1,
          ln2g + l * D_, ln2b + l * D_, be, nullptr, nullptr, bx, bs_);
    }
  }

  hipMemsetAsync(bg_, 0, ((size_t)B_ * NN + 2) * sizeof(float), stream);
  scatter_kernel<<<(B_ * E_) / 256, 256, 0, stream>>>(bs_, eidx, ew, bg_);
  stats_partial<<<(B_ * NN) / 256, 256, 0, stream>>>(bg_, bst);
  final_kernel<<<(NTOT * D_) / 256, 256, 0, stream>>>(bg_, bst, bng, bnb, lgw, lgb, out);
}

// Round 18
// 485.347 us; speedup vs baseline: 1.0208x; 1.0208x over previous
//
#include <hip/hip_runtime.h>
#include <hip/hip_bf16.h>
#include <math.h>

#define EPS_ 1e-5f
constexpr int B_ = 4, NA = 64, T_ = 128, D_ = 128, H_ = 8, L_ = 3, DFF = 512, E_ = 65536;
constexpr int DH = D_ / H_;        // 16
constexpr int NN = T_ * NA;        // 8192
constexpr int NTOT = B_ * NA * T_; // 32768
constexpr int QLD = 384;           // packed QKV bias stride
constexpr size_t NE_ = (size_t)NTOT * D_;

typedef __bf16 bf16x8 __attribute__((ext_vector_type(8)));
typedef float f32x4 __attribute__((ext_vector_type(4)));

__device__ __forceinline__ void pack_hl(float v, __bf16& hh, __bf16& ll) {
  hh = (__bf16)v;
  ll = (__bf16)(v - (float)hh);
}

// ---------------- embed: x = hist@W + b ; e = x + posenc (+ packed be for attn) ----------------
__global__ __launch_bounds__(256) void embed_kernel(
    const float* __restrict__ hist, const float* __restrict__ w,
    const float* __restrict__ b, float* __restrict__ x, float* __restrict__ e,
    __bf16* __restrict__ ehi, __bf16* __restrict__ elo) {
  int idx = blockIdx.x * 256 + threadIdx.x;
  if (idx >= NTOT * D_) return;
  int d = idx & (D_ - 1);
  int r = idx >> 7;
  int t = r & (T_ - 1);
  const float* hp = hist + (size_t)r * 3;
  float acc = b[d];
  acc += hp[0] * w[0 * D_ + d];
  acc += hp[1] * w[1 * D_ + d];
  acc += hp[2] * w[2 * D_ + d];
  x[idx] = acc;
  int p = d >> 1;
  float ang = (float)t * expf(-logf(10000.f) * (2.f * (float)p) / (float)D_);
  float pe = (d & 1) ? cosf(ang) : sinf(ang);
  float ev = acc + pe;
  e[idx] = ev;
  __bf16 hh, ll;
  pack_hl(ev, hh, ll);
  ehi[idx] = hh;
  elo[idx] = ll;
}

// ---------------- weight split into FRAGMENT-LINEAR bf16 hi/lo ----------------
__global__ __launch_bounds__(256) void convert_weights(
    const float* __restrict__ wq, const float* __restrict__ wk,
    const float* __restrict__ wv, const float* __restrict__ wo,
    const float* __restrict__ w1, const float* __restrict__ w2,
    __bf16* __restrict__ hi, __bf16* __restrict__ lo) {
  const int LW = 196608;
  int idx = blockIdx.x * 256 + threadIdx.x;
  if (idx >= L_ * LW) return;
  int l = idx / LW;
  int rem = idx - l * LW;
  float src;
  int n, k, K, segoff;
  if (rem < 49152) { // qkv
    n = rem >> 7; k = rem & 127; K = 128; segoff = 0;
    int which = n >> 7, nl = n & 127;
    const float* W = (which == 0) ? wq : (which == 1) ? wk : wv;
    src = W[(size_t)l * 16384 + k * 128 + nl];
  } else if (rem < 65536) { // wo
    int r2 = rem - 49152;
    n = r2 >> 7; k = r2 & 127; K = 128; segoff = 49152;
    src = wo[(size_t)l * 16384 + k * 128 + n];
  } else if (rem < 131072) { // w1
    int r2 = rem - 65536;
    n = r2 >> 7; k = r2 & 127; K = 128; segoff = 65536;
    src = w1[(size_t)l * 65536 + k * 512 + n];
  } else { // w2
    int r2 = rem - 131072;
    n = r2 >> 9; k = r2 & 511; K = 512; segoff = 131072;
    src = w2[(size_t)l * 65536 + k * 128 + n];
  }
  int nt = n >> 4, kt = k >> 5;
  int lane = ((k >> 3) & 3) * 16 + (n & 15);
  int j = k & 7;
  int dst = l * LW + segoff + ((nt * (K / 32) + kt) * 64 + lane) * 8 + j;
  __bf16 h = (__bf16)src;
  hi[dst] = h;
  lo[dst] = (__bf16)(src - (float)h);
}

// ---------------- pack QKV biases ----------------
__global__ __launch_bounds__(256) void bias_pack(
    const float* __restrict__ bq, const float* __restrict__ bk,
    const float* __restrict__ bv, float* __restrict__ pb) {
  int idx = blockIdx.x * 256 + threadIdx.x;
  if (idx >= L_ * QLD) return;
  int l = idx / QLD, n = idx - l * QLD;
  int which = n >> 7, nl = n & 127;
  const float* src = (which == 0) ? bq : (which == 1) ? bk : bv;
  pb[idx] = src[l * 128 + nl];
}

__device__ __forceinline__ void split8(const float* __restrict__ p,
                                       bf16x8& hi, bf16x8& lo) {
  float4 x0 = *(const float4*)p;
  float4 x1 = *(const float4*)(p + 4);
  float xv[8] = {x0.x, x0.y, x0.z, x0.w, x1.x, x1.y, x1.z, x1.w};
#pragma unroll
  for (int j = 0; j < 8; ++j) {
    __bf16 h = (__bf16)xv[j];
    hi[j] = h;
    lo[j] = (__bf16)(xv[j] - (float)h);
  }
}

// ---------------- MFMA GEMM, 128x128 tile, frag-linear W [r25: 1-D grid, XCD co-location] ----------------
template <int EPI, int K>
__global__ __launch_bounds__(256) void gemm_big(
    const float* __restrict__ A, int lda,
    const __bf16* __restrict__ Whi, const __bf16* __restrict__ Wlo,
    const float* __restrict__ bias,
    float* __restrict__ C, int ldc) {
  const int wave = threadIdx.x >> 6;
  const int lane = threadIdx.x & 63;
  const int m16 = lane & 15;
  const int quad = lane >> 4;
  const int wrow = wave >> 1, wcol = wave & 1;
  const int by = blockIdx.x & 255;  // row-block (NTOT/128 = 256)
  const int bx = blockIdx.x >> 8;   // col-block
  const int row0 = by * 128 + wrow * 64;
  const int col0 = bx * 128 + wcol * 64;
  const int ctb = col0 >> 4;

  f32x4 acc[4][4] = {};
#pragma unroll
  for (int k0 = 0; k0 < K; k0 += 32) {
    bf16x8 ahi[4], alo[4];
#pragma unroll
    for (int mf = 0; mf < 4; ++mf)
      split8(A + (size_t)(row0 + mf * 16 + m16) * lda + k0 + quad * 8, ahi[mf], alo[mf]);
    bf16x8 bhi[4], blo[4];
#pragma unroll
    for (int nf = 0; nf < 4; ++nf) {
      size_t off = ((size_t)(ctb + nf) * (K / 32) + (k0 >> 5)) * 512 + lane * 8;
      bhi[nf] = *(const bf16x8*)(Whi + off);
      blo[nf] = *(const bf16x8*)(Wlo + off);
    }
#pragma unroll
    for (int mf = 0; mf < 4; ++mf)
#pragma unroll
      for (int nf = 0; nf < 4; ++nf) {
        acc[mf][nf] = __builtin_amdgcn_mfma_f32_16x16x32_bf16(ahi[mf], bhi[nf], acc[mf][nf], 0, 0, 0);
        acc[mf][nf] = __builtin_amdgcn_mfma_f32_16x16x32_bf16(ahi[mf], blo[nf], acc[mf][nf], 0, 0, 0);
        acc[mf][nf] = __builtin_amdgcn_mfma_f32_16x16x32_bf16(alo[mf], bhi[nf], acc[mf][nf], 0, 0, 0);
      }
  }
#pragma unroll
  for (int mf = 0; mf < 4; ++mf)
#pragma unroll
    for (int nf = 0; nf < 4; ++nf) {
      int c = col0 + nf * 16 + m16;
      float bj = bias[c];
#pragma unroll
      for (int reg = 0; reg < 4; ++reg) {
        int r = row0 + mf * 16 + quad * 4 + reg;
        float v = acc[mf][nf][reg] + bj;
        if (EPI == 1) v = fmaxf(v, 0.f);
        C[(size_t)r * ldc + c] = v;
      }
    }
}

// ---------------- GEMM + bias + resid + LayerNorm; block 64x128, register A [r12] ----------------
template <int K>
__global__ __launch_bounds__(256) void gemm_ln(
    const float* __restrict__ A, int lda,
    const __bf16* __restrict__ Whi, const __bf16* __restrict__ Wlo,
    const float* __restrict__ bias, const float* __restrict__ resid,
    const float* __restrict__ lng, const float* __restrict__ lnb,
    float* __restrict__ C) {
  const int wave = threadIdx.x >> 6;
  const int lane = threadIdx.x & 63;
  const int m16 = lane & 15;
  const int quad = lane >> 4;
  const int wrow = wave >> 1, wcol = wave & 1;
  const int row0 = blockIdx.y * 64 + wrow * 32;
  const int col0 = wcol * 64;
  const int ctb = wcol * 4;

  f32x4 acc[2][4] = {};
#pragma unroll
  for (int k0 = 0; k0 < K; k0 += 32) {
    bf16x8 ahi[2], alo[2];
#pragma unroll
    for (int mf = 0; mf < 2; ++mf)
      split8(A + (size_t)(row0 + mf * 16 + m16) * lda + k0 + quad * 8, ahi[mf], alo[mf]);
    bf16x8 bhi[4], blo[4];
#pragma unroll
    for (int nf = 0; nf < 4; ++nf) {
      size_t off = ((size_t)(ctb + nf) * (K / 32) + (k0 >> 5)) * 512 + lane * 8;
      bhi[nf] = *(const bf16x8*)(Whi + off);
      blo[nf] = *(const bf16x8*)(Wlo + off);
    }
#pragma unroll
    for (int mf = 0; mf < 2; ++mf)
#pragma unroll
      for (int nf = 0; nf < 4; ++nf) {
        acc[mf][nf] = __builtin_amdgcn_mfma_f32_16x16x32_bf16(ahi[mf], bhi[nf], acc[mf][nf], 0, 0, 0);
        acc[mf][nf] = __builtin_amdgcn_mfma_f32_16x16x32_bf16(ahi[mf], blo[nf], acc[mf][nf], 0, 0, 0);
        acc[mf][nf] = __builtin_amdgcn_mfma_f32_16x16x32_bf16(alo[mf], bhi[nf], acc[mf][nf], 0, 0, 0);
      }
  }
  __shared__ float rs[64][2], rq[64][2];
#pragma unroll
  for (int mf = 0; mf < 2; ++mf)
#pragma unroll
    for (int reg = 0; reg < 4; ++reg) {
      int lr = wrow * 32 + mf * 16 + quad * 4 + reg;
      int gr = blockIdx.y * 64 + lr;
      float s = 0.f, qq = 0.f;
#pragma unroll
      for (int nf = 0; nf < 4; ++nf) {
        int c = col0 + nf * 16 + m16;
        float v = acc[mf][nf][reg] + bias[c] + resid[(size_t)gr * 128 + c];
        acc[mf][nf][reg] = v;
        s += v;
        qq += v * v;
      }
#pragma unroll
      for (int off = 1; off < 16; off <<= 1) {
        s += __shfl_xor(s, off, 64);
        qq += __shfl_xor(qq, off, 64);
      }
      if (m16 == 0) { rs[lr][wcol] = s; rq[lr][wcol] = qq; }
    }
  __syncthreads();
#pragma unroll
  for (int mf = 0; mf < 2; ++mf)
#pragma unroll
    for (int reg = 0; reg < 4; ++reg) {
      int lr = wrow * 32 + mf * 16 + quad * 4 + reg;
      int gr = blockIdx.y * 64 + lr;
      float mean = (rs[lr][0] + rs[lr][1]) * (1.f / 128.f);
      float var = (rq[lr][0] + rq[lr][1]) * (1.f / 128.f) - mean * mean;
      float rstd = rsqrtf(var + EPS_);
#pragma unroll
      for (int nf = 0; nf < 4; ++nf) {
        int c = col0 + nf * 16 + m16;
        C[(size_t)gr * 128 + c] = (acc[mf][nf][reg] - mean) * rstd * lng[c] + lnb[c];
      }
    }
}

// ---------------- FF2 + LN [r28: PACK emits packed be for next-layer attn] ----------------
template <int SDOT, int PACK>
__global__ __launch_bounds__(256) void ff2_ln(
    const float* __restrict__ A, // ffmid [M][512]
    const __bf16* __restrict__ Whi, const __bf16* __restrict__ Wlo,
    const float* __restrict__ bias, const float* __restrict__ resid,
    const float* __restrict__ lng, const float* __restrict__ lnb,
    float* __restrict__ C, __bf16* __restrict__ Chi, __bf16* __restrict__ Clo,
    const float* __restrict__ bx, float* __restrict__ sdst) {
  const int wave = threadIdx.x >> 6;
  const int lane = threadIdx.x & 63;
  const int m16 = lane & 15;
  const int quad = lane >> 4;
  const int wrow = wave >> 1, wcol = wave & 1;
  const int grow0 = blockIdx.y * 64;
  const int lrow0 = wrow * 32;
  const int col0 = wcol * 64;
  const int ctb = wcol * 4;

  __shared__ float As[64][129];

  f32x4 acc[2][4] = {};
  for (int kc = 0; kc < 4; ++kc) {
    if (kc) __syncthreads();
#pragma unroll
    for (int u = 0; u < 8; ++u) {
      int unit = threadIdx.x + u * 256;
      int r = unit >> 5, c4 = unit & 31;
      float4 v = *(const float4*)(A + (size_t)(grow0 + r) * 512 + kc * 128 + c4 * 4);
      As[r][c4 * 4 + 0] = v.x;
      As[r][c4 * 4 + 1] = v.y;
      As[r][c4 * 4 + 2] = v.z;
      As[r][c4 * 4 + 3] = v.w;
    }
    __syncthreads();
#pragma unroll
    for (int kt = 0; kt < 4; ++kt) {
      bf16x8 ahi[2], alo[2];
#pragma unroll
      for (int mf = 0; mf < 2; ++mf)
        split8(&As[lrow0 + mf * 16 + m16][kt * 32 + quad * 8], ahi[mf], alo[mf]);
      bf16x8 bhi[4], blo[4];
#pragma unroll
      for (int nf = 0; nf < 4; ++nf) {
        size_t off = ((size_t)(ctb + nf) * 16 + (kc * 4 + kt)) * 512 + lane * 8;
        bhi[nf] = *(const bf16x8*)(Whi + off);
        blo[nf] = *(const bf16x8*)(Wlo + off);
      }
#pragma unroll
      for (int mf = 0; mf < 2; ++mf)
#pragma unroll
        for (int nf = 0; nf < 4; ++nf) {
          acc[mf][nf] = __builtin_amdgcn_mfma_f32_16x16x32_bf16(ahi[mf], bhi[nf], acc[mf][nf], 0, 0, 0);
          acc[mf][nf] = __builtin_amdgcn_mfma_f32_16x16x32_bf16(ahi[mf], blo[nf], acc[mf][nf], 0, 0, 0);
          acc[mf][nf] = __builtin_amdgcn_mfma_f32_16x16x32_bf16(alo[mf], bhi[nf], acc[mf][nf], 0, 0, 0);
        }
    }
  }
  __shared__ float rs[64][2], rq[64][2];
  __shared__ float sd[64][2];
#pragma unroll
  for (int mf = 0; mf < 2; ++mf)
#pragma unroll
    for (int reg = 0; reg < 4; ++reg) {
      int lr = lrow0 + mf * 16 + quad * 4 + reg;
      int gr = grow0 + lr;
      float s = 0.f, qq = 0.f;
#pragma unroll
      for (int nf = 0; nf < 4; ++nf) {
        int c = col0 + nf * 16 + m16;
        float v = acc[mf][nf][reg] + bias[c] + resid[(size_t)gr * 128 + c];
        acc[mf][nf][reg] = v;
        s += v;
        qq += v * v;
      }
#pragma unroll
      for (int off = 1; off < 16; off <<= 1) {
        s += __shfl_xor(s, off, 64);
        qq += __shfl_xor(qq, off, 64);
      }
      if (m16 == 0) { rs[lr][wcol] = s; rq[lr][wcol] = qq; }
    }
  __syncthreads();
#pragma unroll
  for (int mf = 0; mf < 2; ++mf)
#pragma unroll
    for (int reg = 0; reg < 4; ++reg) {
      int lr = lrow0 + mf * 16 + quad * 4 + reg;
      int gr = grow0 + lr;
      float mean = (rs[lr][0] + rs[lr][1]) * (1.f / 128.f);
      float var = (rq[lr][0] + rq[lr][1]) * (1.f / 128.f) - mean * mean;
      float rstd = rsqrtf(var + EPS_);
      float sdp = 0.f;
#pragma unroll
      for (int nf = 0; nf < 4; ++nf) {
        int c = col0 + nf * 16 + m16;
        float v = (acc[mf][nf][reg] - mean) * rstd * lng[c] + lnb[c];
        size_t oidx = (size_t)gr * 128 + c;
        C[oidx] = v;
        if (PACK) {
          __bf16 hh, ll;
          pack_hl(v, hh, ll);
          Chi[oidx] = hh;
          Clo[oidx] = ll;
        }
        if (SDOT) sdp += v * bx[oidx];
      }
      if (SDOT) {
#pragma unroll
        for (int off = 1; off < 16; off <<= 1) sdp += __shfl_xor(sdp, off, 64);
        if (m16 == 0) sd[lr][wcol] = sdp;
      }
    }
  if (SDOT) {
    __syncthreads();
    if (threadIdx.x < 64) {
      int lr = threadIdx.x;
      int gr = grow0 + lr;
      float sv = sd[lr][0] + sd[lr][1];
      int t = gr & (T_ - 1);
      int bn = gr >> 7;
      int n = bn & (NA - 1);
      int b = bn >> 6;
      sdst[(size_t)b * NN + t * NA + n] = sv;
    }
  }
}

// ---------------- FUSED QKV-GEMM + attention [r28: packed-A input; r25 XCD decode] ----------------
__global__ __launch_bounds__(256) void attn_fused(
    const __bf16* __restrict__ Ahi, const __bf16* __restrict__ Alo, // be packed [NTOT][128]
    const __bf16* __restrict__ Whi, const __bf16* __restrict__ Wlo, // layer qkv segment
    const float* __restrict__ pb,      // packed qkv bias [384]
    float* __restrict__ O) {           // [NTOT][128]
  const int h = blockIdx.x >> 8;      // head-major
  const int bn = blockIdx.x & 255;    // same-bn blocks share an XCD
  const int wave = threadIdx.x >> 6;
  const int lane = threadIdx.x & 63;
  const int m16 = lane & 15;
  const int quad = lane >> 4;
  const int row0 = wave * 32;
  const __bf16* Abh = Ahi + (size_t)bn * T_ * 128;
  const __bf16* Abl = Alo + (size_t)bn * T_ * 128;

  __shared__ __bf16 Plds[4][32][136];
  __shared__ __bf16 KVH[8][32][8], KVL[8][32][8]; // K then (post-QK^T) V, time-shared
  __bf16* QHw = &Plds[wave][0][0];                // wave-private Q: [2][32][8] (aliased)
  __bf16* QLw = QHw + 512;
  __bf16* kvh = &KVH[0][0][0];
  __bf16* kvl = &KVL[0][0][0];

  // ---- mini-GEMM: rows [row0, row0+32) x {Q,K,V} cols [h*16, h*16+16)
  f32x4 qkv[2][3] = {}; // [mf][seg]
#pragma unroll
  for (int k0 = 0; k0 < 128; k0 += 32) {
    bf16x8 ahi[2], alo[2];
#pragma unroll
    for (int mf = 0; mf < 2; ++mf) {
      size_t aoff = (size_t)(row0 + mf * 16 + m16) * 128 + k0 + quad * 8;
      ahi[mf] = *(const bf16x8*)(Abh + aoff);
      alo[mf] = *(const bf16x8*)(Abl + aoff);
    }
    bf16x8 bhi[3], blo[3];
#pragma unroll
    for (int s = 0; s < 3; ++s) {
      size_t off = ((size_t)(s * 8 + h) * 4 + (k0 >> 5)) * 512 + lane * 8; // ctb = s*8+h
      bhi[s] = *(const bf16x8*)(Whi + off);
      blo[s] = *(const bf16x8*)(Wlo + off);
    }
#pragma unroll
    for (int mf = 0; mf < 2; ++mf)
#pragma unroll
      for (int s = 0; s < 3; ++s) {
        qkv[mf][s] = __builtin_amdgcn_mfma_f32_16x16x32_bf16(ahi[mf], bhi[s], qkv[mf][s], 0, 0, 0);
        qkv[mf][s] = __builtin_amdgcn_mfma_f32_16x16x32_bf16(ahi[mf], blo[s], qkv[mf][s], 0, 0, 0);
        qkv[mf][s] = __builtin_amdgcn_mfma_f32_16x16x32_bf16(alo[mf], bhi[s], qkv[mf][s], 0, 0, 0);
      }
  }

  // ---- stage Q (wave-private) + K (shared); V stays in registers until after QK^T
#pragma unroll
  for (int mf = 0; mf < 2; ++mf)
#pragma unroll
    for (int reg = 0; reg < 4; ++reg) {
      const int tl = mf * 16 + quad * 4 + reg; // local row 0..31
      const int t = row0 + tl;                 // block row 0..127
      const int dh = m16;
      { // Q -> wave-private
        float v = qkv[mf][0][reg] + pb[h * 16 + dh];
        __bf16 hh, ll;
        pack_hl(v, hh, ll);
        int idx = mf * 256 + ((dh >> 3) * 16 + (tl & 15)) * 8 + (dh & 7);
        QHw[idx] = hh;
        QLw[idx] = ll;
      }
      { // K -> shared (K layout: [t>>4][(dh>>3)*16 + (t&15)][dh&7])
        float v = qkv[mf][1][reg] + pb[128 + h * 16 + dh];
        __bf16 hh, ll;
        pack_hl(v, hh, ll);
        int idx = ((t >> 4) * 32 + (dh >> 3) * 16 + (t & 15)) * 8 + (dh & 7);
        kvh[idx] = hh;
        kvl[idx] = ll;
      }
    }

  // ---- read own Q A-frags back (wave-private; same-wave LDS dependency)
  bf16x8 qhi[2], qlo[2];
#pragma unroll
  for (int mf = 0; mf < 2; ++mf) {
    if (quad < 2) {
      int idx = mf * 256 + (quad * 16 + m16) * 8;
      qhi[mf] = *(const bf16x8*)&QHw[idx];
      qlo[mf] = *(const bf16x8*)&QLw[idx];
    } else {
#pragma unroll
      for (int j = 0; j < 8; ++j) { qhi[mf][j] = (__bf16)0.f; qlo[mf][j] = (__bf16)0.f; }
    }
  }
  __syncthreads(); // K staging visible to all waves

  f32x4 acc[2][8] = {};
#pragma unroll
  for (int nf = 0; nf < 8; ++nf) {
    bf16x8 khi, klo;
    if (quad < 2) {
      khi = *(const bf16x8*)&kvh[(nf * 32 + lane) * 8]; // lane in [0,32)
      klo = *(const bf16x8*)&kvl[(nf * 32 + lane) * 8];
    } else {
#pragma unroll
      for (int j = 0; j < 8; ++j) { khi[j] = (__bf16)0.f; klo[j] = (__bf16)0.f; }
    }
#pragma unroll
    for (int mf = 0; mf < 2; ++mf) {
      acc[mf][nf] = __builtin_amdgcn_mfma_f32_16x16x32_bf16(qhi[mf], khi, acc[mf][nf], 0, 0, 0);
      acc[mf][nf] = __builtin_amdgcn_mfma_f32_16x16x32_bf16(qhi[mf], klo, acc[mf][nf], 0, 0, 0);
      acc[mf][nf] = __builtin_amdgcn_mfma_f32_16x16x32_bf16(qlo[mf], khi, acc[mf][nf], 0, 0, 0);
    }
  }
  __syncthreads(); // all waves done reading K -> region reusable for V

  // ---- stage V into the K region (V layout: [(t>>5)*64 + (rem>>3)*16 + dh][rem&7])
#pragma unroll
  for (int mf = 0; mf < 2; ++mf)
#pragma unroll
    for (int reg = 0; reg < 4; ++reg) {
      const int t = row0 + mf * 16 + quad * 4 + reg;
      const int dh = m16;
      float v = qkv[mf][2][reg] + pb[256 + h * 16 + dh];
      __bf16 hh, ll;
      pack_hl(v, hh, ll);
      int kc = t >> 5, rem = t & 31;
      int idx = (kc * 64 + (rem >> 3) * 16 + dh) * 8 + (rem & 7);
      kvh[idx] = hh;
      kvl[idx] = ll;
    }

  // ---- softmax (register-only; overlaps other waves' V stores)
  const float scale = 0.25f;
#pragma unroll
  for (int mf = 0; mf < 2; ++mf)
#pragma unroll
    for (int reg = 0; reg < 4; ++reg) {
      float mx = -1e30f;
#pragma unroll
      for (int nf = 0; nf < 8; ++nf) mx = fmaxf(mx, acc[mf][nf][reg]);
#pragma unroll
      for (int off = 1; off < 16; off <<= 1) mx = fmaxf(mx, __shfl_xor(mx, off, 64));
      float sum = 0.f;
#pragma unroll
      for (int nf = 0; nf < 8; ++nf) {
        float e = __expf((acc[mf][nf][reg] - mx) * scale);
        acc[mf][nf][reg] = e;
        sum += e;
      }
#pragma unroll
      for (int off = 1; off < 16; off <<= 1) sum += __shfl_xor(sum, off, 64);
      float inv = 1.f / sum;
#pragma unroll
      for (int nf = 0; nf < 8; ++nf) acc[mf][nf][reg] *= inv;
    }
  __syncthreads(); // V staging visible to all waves

#pragma unroll
  for (int mf = 0; mf < 2; ++mf)
#pragma unroll
    for (int nf = 0; nf < 8; ++nf)
#pragma unroll
      for (int reg = 0; reg < 4; ++reg)
        Plds[wave][mf * 16 + quad * 4 + reg][nf * 16 + m16] = (__bf16)acc[mf][nf][reg];

  f32x4 oacc[2] = {};
#pragma unroll
  for (int kc = 0; kc < 4; ++kc) {
    bf16x8 pa0 = *(const bf16x8*)&Plds[wave][m16][kc * 32 + quad * 8];
    bf16x8 pa1 = *(const bf16x8*)&Plds[wave][16 + m16][kc * 32 + quad * 8];
    bf16x8 vhi = *(const bf16x8*)&kvh[(kc * 64 + lane) * 8];
    bf16x8 vlo = *(const bf16x8*)&kvl[(kc * 64 + lane) * 8];
    oacc[0] = __builtin_amdgcn_mfma_f32_16x16x32_bf16(pa0, vhi, oacc[0], 0, 0, 0);
    oacc[0] = __builtin_amdgcn_mfma_f32_16x16x32_bf16(pa0, vlo, oacc[0], 0, 0, 0);
    oacc[1] = __builtin_amdgcn_mfma_f32_16x16x32_bf16(pa1, vhi, oacc[1], 0, 0, 0);
    oacc[1] = __builtin_amdgcn_mfma_f32_16x16x32_bf16(pa1, vlo, oacc[1], 0, 0, 0);
  }

#pragma unroll
  for (int mf = 0; mf < 2; ++mf)
#pragma unroll
    for (int reg = 0; reg < 4; ++reg) {
      int r = row0 + mf * 16 + quad * 4 + reg;
      O[((size_t)bn * T_ + r) * 128 + h * 16 + m16] = oacc[mf][reg];
    }
}

// ---------------- edge scatter ----------------
__global__ __launch_bounds__(256) void scatter_kernel(
    const float* __restrict__ s, const int* __restrict__ ei,
    const float* __restrict__ ew, float* __restrict__ g) {
  int idx = blockIdx.x * 256 + threadIdx.x;
  if (idx >= B_ * E_) return;
  int b = idx >> 16;
  int e = idx & (E_ - 1);
  int src = ei[(size_t)b * 2 * E_ + e];
  int dst = ei[(size_t)b * 2 * E_ + E_ + e];
  float w = ew[(size_t)b * E_ + e];
  atomicAdd(&g[(size_t)b * NN + dst], w * s[(size_t)b * NN + src]);
}

// ---------------- partial sums for global mean/var ----------------
__global__ __launch_bounds__(256) void stats_partial(
    const float* __restrict__ g, float* __restrict__ st) {
  int i = blockIdx.x * 256 + threadIdx.x;
  float v = g[i];
  float sum = v, sq = v * v;
#pragma unroll
  for (int off = 32; off; off >>= 1) {
    sum += __shfl_down(sum, off, 64);
    sq += __shfl_down(sq, off, 64);
  }
  __shared__ float s1[4], s2[4];
  int w = threadIdx.x >> 6;
  if ((threadIdx.x & 63) == 0) { s1[w] = sum; s2[w] = sq; }
  __syncthreads();
  if (threadIdx.x == 0) {
    atomicAdd(&st[0], s1[0] + s1[1] + s1[2] + s1[3]);
    atomicAdd(&st[1], s2[0] + s2[1] + s2[2] + s2[3]);
  }
}

// ---------------- final (fp32 out) ----------------
__global__ __launch_bounds__(256) void final_kernel(
    const float* __restrict__ g, const float* __restrict__ st,
    const float* __restrict__ bng, const float* __restrict__ bnb,
    const float* __restrict__ lw, const float* __restrict__ lb,
    float* __restrict__ out) {
  int idx = blockIdx.x * 256 + threadIdx.x;
  if (idx >= NTOT * D_) return;
  int d = idx & (D_ - 1);
  int r = idx >> 7;
  int t = r & (T_ - 1);
  int bn = r >> 7;
  int n = bn & (NA - 1);
  int b = bn >> 6;
  const float invn = 1.f / (float)(B_ * NN);
  float m = st[0] * invn;
  float var = st[1] * invn - m * m;
  float rs = rsqrtf(var + EPS_);
  float gv = g[(size_t)b * NN + t * NA + n];
  float val = (gv - m) * rs * bng[0] + bnb[0];
  out[idx] = val * lw[d] + lb[d];
}

extern "C" void kernel_launch(void* const* d_in, const int* in_sizes, int n_in,
                              void* d_out, int out_size, void* d_ws, size_t ws_size,
                              hipStream_t stream) {
  const float* hist = (const float*)d_in[0];
  const int* eidx = (const int*)d_in[1];
  const float* ew = (const float*)d_in[2];
  const float* hw = (const float*)d_in[3];
  const float* hb = (const float*)d_in[4];
  const float* wq = (const float*)d_in[5];
  const float* bq = (const float*)d_in[6];
  const float* wk = (const float*)d_in[7];
  const float* bk = (const float*)d_in[8];
  const float* wv = (const float*)d_in[9];
  const float* bv = (const float*)d_in[10];
  const float* wo = (const float*)d_in[11];
  const float* bo = (const float*)d_in[12];
  const float* ln1g = (const float*)d_in[13];
  const float* ln1b = (const float*)d_in[14];
  const float* w1 = (const float*)d_in[15];
  const float* b1 = (const float*)d_in[16];
  const float* w2 = (const float*)d_in[17];
  const float* b2 = (const float*)d_in[18];
  const float* ln2g = (const float*)d_in[19];
  const float* ln2b = (const float*)d_in[20];
  const float* bng = (const float*)d_in[21];
  const float* bnb = (const float*)d_in[22];
  const float* lgw = (const float*)d_in[23];
  const float* lgb = (const float*)d_in[24];
  float* out = (float*)d_out;

  float* ws = (float*)d_ws;
  const size_t NE = NE_;
  float* bx = ws + 0 * NE;
  float* be = ws + 1 * NE;
  float* h1 = ws + 2 * NE;
  float* obuf = ws + 3 * NE;  // attention output [row][128]
  float* ffmid = ws + 3 * NE; // 4NE, overlaps dead obuf (sequential deps)
  float* bs_ = ws + 7 * NE;
  float* bg_ = bs_ + NTOT;
  float* bst = bg_ + NTOT;
  float* pbias = bst + 2;
  const int LW = 196608;
  __bf16* whiB = (__bf16*)(pbias + L_ * QLD);
  __bf16* wloB = whiB + (size_t)L_ * LW;
  __bf16* behi = wloB + (size_t)L_ * LW; // packed be [NTOT][128]
  __bf16* belo = behi + NE;

  convert_weights<<<(L_ * LW + 255) / 256, 256, 0, stream>>>(
      wq, wk, wv, wo, w1, w2, whiB, wloB);
  bias_pack<<<(L_ * QLD + 255) / 256, 256, 0, stream>>>(bq, bk, bv, pbias);
  embed_kernel<<<(NTOT * D_) / 256, 256, 0, stream>>>(hist, hw, hb, bx, be, behi, belo);

  for (int l = 0; l < L_; ++l) {
    const __bf16* hiL = whiB + (size_t)l * LW;
    const __bf16* loL = wloB + (size_t)l * LW;
    attn_fused<<<B_ * NA * H_, 256, 0, stream>>>(
        behi, belo, hiL, loL, pbias + l * QLD, obuf);
    gemm_ln<128><<<dim3(1, NTOT / 64), 256, 0, stream>>>(
        obuf, 128, hiL + 49152, loL + 49152, bo + l * D_, be,
        ln1g + l * D_, ln1b + l * D_, h1);
    gemm_big<1, 128><<<4 * (NTOT / 128), 256, 0, stream>>>(
        h1, 128, hiL + 65536, loL + 65536, b1 + l * DFF, ffmid, 512);
    if (l < L_ - 1) {
      ff2_ln<0, 1><<<dim3(1, NTOT / 64), 256, 0, stream>>>(
          ffmid, hiL + 131072, loL + 131072, b2 + l * D_, h1,
          ln2g + l * D_, ln2b + l * D_, be, behi, belo, nullptr, nullptr);
    } else {
      ff2_ln<1, 0><<<dim3(1, NTOT / 64), 256, 0, stream>>>(
          ffmid, hiL + 131072, loL + 131072, b2 + l * D_, h1,
          ln2g + l * D_, ln2b + l * D_, be, nullptr, nullptr, bx, bs_);
    }
  }

  hipMemsetAsync(bg_, 0, ((size_t)B_ * NN + 2) * sizeof(float), stream);
  scatter_kernel<<<(B_ * E_) / 256, 256, 0, stream>>>(bs_, eidx, ew, bg_);
  stats_partial<<<(B_ * NN) / 256, 256, 0, stream>>>(bg_, bst);
  final_kernel<<<(NTOT * D_) / 256, 256, 0, stream>>>(bg_, bst, bng, bnb, lgw, lgb, out);
}